// Round 3
// baseline (461.805 us; speedup 1.0000x reference)
//
#include <hip/hip_runtime.h>
#include <math.h>

#define D_MODEL 1024
#define NHEADS  16
#define DHEAD   64
#define BATCH   8
#define SEQ     1024
#define MROWS   (BATCH*SEQ)   // 8192

typedef short          bf16x8 __attribute__((ext_vector_type(8)));
typedef unsigned short u16x8  __attribute__((ext_vector_type(8)));
typedef float          f32x4  __attribute__((ext_vector_type(4)));

typedef __attribute__((address_space(1))) void* gvp;   // global
typedef __attribute__((address_space(3))) void* svp;   // LDS

__device__ __forceinline__ unsigned short f2bf(float f) {
    unsigned int u = __float_as_uint(f);
    u = u + 0x7fffu + ((u >> 16) & 1u);      // round-to-nearest-even
    return (unsigned short)(u >> 16);
}

// ---------------------------------------------------------------------------
// fp32 -> bf16 elementwise convert for queries/keys/values. 8 elems/thread.
// ---------------------------------------------------------------------------
__global__ __launch_bounds__(256) void convert3(
    const float* __restrict__ q, const float* __restrict__ k, const float* __restrict__ v,
    unsigned short* __restrict__ oq, unsigned short* __restrict__ ok, unsigned short* __restrict__ ov)
{
    const float* in; unsigned short* out;
    if (blockIdx.z == 0)      { in = q; out = oq; }
    else if (blockIdx.z == 1) { in = k; out = ok; }
    else                      { in = v; out = ov; }
    const size_t i = ((size_t)blockIdx.x * 256 + threadIdx.x) * 8;
    const float4 a = *(const float4*)(in + i);
    const float4 b = *(const float4*)(in + i + 4);
    u16x8 o;
    o[0] = f2bf(a.x); o[1] = f2bf(a.y); o[2] = f2bf(a.z); o[3] = f2bf(a.w);
    o[4] = f2bf(b.x); o[5] = f2bf(b.y); o[6] = f2bf(b.z); o[7] = f2bf(b.w);
    *(u16x8*)(out + i) = o;
}

// ---------------------------------------------------------------------------
// Transpose-convert weights to bf16 Bt[n][k] layout.
// z = 0..2: Wq/Wk/Wv ([H][1024][64], virtual col n = h*64+e); z = 3..4: W1/W2.
// grid: (32, 32, 5), block 256 (32x8).
// ---------------------------------------------------------------------------
__global__ __launch_bounds__(256) void tconvW(
    const float* __restrict__ Wq, const float* __restrict__ Wk, const float* __restrict__ Wv,
    const float* __restrict__ W1, const float* __restrict__ W2,
    unsigned short* __restrict__ Tq, unsigned short* __restrict__ Tk, unsigned short* __restrict__ Tv,
    unsigned short* __restrict__ T1, unsigned short* __restrict__ T2)
{
    const int z = blockIdx.z;
    const float* in; unsigned short* out;
    if (z == 0)      { in = Wq; out = Tq; }
    else if (z == 1) { in = Wk; out = Tk; }
    else if (z == 2) { in = Wv; out = Tv; }
    else if (z == 3) { in = W1; out = T1; }
    else             { in = W2; out = T2; }
    const int proj = (z < 3);

    __shared__ float t[32][33];
    const int c0 = blockIdx.x * 32, r0 = blockIdx.y * 32;
    const int tx = threadIdx.x & 31, ty = threadIdx.x >> 5;

    #pragma unroll
    for (int i = 0; i < 4; ++i) {
        const int r = r0 + ty + i * 8;
        const size_t addr = proj
            ? ((size_t)(c0 >> 6) * (D_MODEL * DHEAD) + (size_t)r * DHEAD + (c0 & 63) + tx)
            : ((size_t)r * D_MODEL + c0 + tx);
        t[ty + i * 8][tx] = in[addr];
    }
    __syncthreads();
    #pragma unroll
    for (int i = 0; i < 4; ++i) {
        const int n = c0 + ty + i * 8;                 // output row (col of W)
        out[(size_t)n * D_MODEL + r0 + tx] = f2bf(t[tx][ty + i * 8]);
    }
}

// ---------------------------------------------------------------------------
// bf16 MFMA GEMM (m97 structure): C = A . Bt^T, tile 128x128, BK=32, 4 waves.
// Linear LDS [128][32], staged via global_load_lds width=16.
// EPI: 0 = bias->bf16, 1 = bias->bf16 transposed per-head (Vt, ushort4 packed),
//      2 = bias+relu->bf16, 3 = bias+res(f32)->f32
// grid: (M/128, N/128) = (64, 8)
// ---------------------------------------------------------------------------
template<int EPI>
__global__ __launch_bounds__(256) void gemm128(
    const unsigned short* __restrict__ A,
    const unsigned short* __restrict__ Bt,
    const float* __restrict__ bias,
    const float* __restrict__ res,
    void* __restrict__ outp)
{
    const int m0 = blockIdx.x * 128;
    const int n0 = blockIdx.y * 128;
    const int tid = threadIdx.x;
    const int l  = tid & 63;
    const int w  = tid >> 6;
    const int wr = w >> 1, wc = w & 1;
    const int lr = l & 15, lk = l >> 4;

    __shared__ unsigned short As[128 * 32];
    __shared__ unsigned short Bs[128 * 32];

    f32x4 acc[4][4] = {};

    // global_load_lds map: chunk c = w*2+i (0..7) covers LDS bytes c*1024 + lane*16
    // -> row = c*16 + l/4, col = (l&3)*8 of the [128][32] tile.
    const int r_a = (l >> 2);            // 0..15 within chunk
    const int c_a = (l & 3) * 8;

    for (int k0 = 0; k0 < D_MODEL; k0 += 32) {
        #pragma unroll
        for (int i = 0; i < 2; ++i) {
            const int c   = w * 2 + i;
            const int row = c * 16 + r_a;
            __builtin_amdgcn_global_load_lds(
                (gvp)(void*)&A [(size_t)(m0 + row) * D_MODEL + k0 + c_a],
                (svp)(void*)&As[c * 512], 16, 0, 0);
            __builtin_amdgcn_global_load_lds(
                (gvp)(void*)&Bt[(size_t)(n0 + row) * D_MODEL + k0 + c_a],
                (svp)(void*)&Bs[c * 512], 16, 0, 0);
        }
        __syncthreads();   // drains vmcnt -> tiles ready

        bf16x8 af[4], bf[4];
        #pragma unroll
        for (int m = 0; m < 4; ++m)
            af[m] = *(const bf16x8*)&As[(wr * 64 + m * 16 + lr) * 32 + lk * 8];
        #pragma unroll
        for (int n = 0; n < 4; ++n)
            bf[n] = *(const bf16x8*)&Bs[(wc * 64 + n * 16 + lr) * 32 + lk * 8];
        #pragma unroll
        for (int m = 0; m < 4; ++m)
            #pragma unroll
            for (int n = 0; n < 4; ++n)
                acc[m][n] = __builtin_amdgcn_mfma_f32_16x16x32_bf16(af[m], bf[n], acc[m][n], 0, 0, 0);
        __syncthreads();   // protect LDS before next iteration's loads
    }

    const int col_base = n0 + wc * 64;
    const int row_base = m0 + wr * 64;
    #pragma unroll
    for (int n = 0; n < 4; ++n) {
        const int col  = col_base + n * 16 + lr;
        const float bc = bias[col];
        #pragma unroll
        for (int m = 0; m < 4; ++m) {
            if (EPI == 1) {
                // rows lk*4 .. +3 are 4 consecutive seq positions -> pack 8B store
                const int row0 = row_base + m * 16 + lk * 4;
                const int b = row0 >> 10, nn0 = row0 & 1023;
                ushort4 pk;
                pk.x = f2bf(acc[m][n][0] + bc);
                pk.y = f2bf(acc[m][n][1] + bc);
                pk.z = f2bf(acc[m][n][2] + bc);
                pk.w = f2bf(acc[m][n][3] + bc);
                *(ushort4*)&((unsigned short*)outp)[((size_t)b * 1024 + col) * SEQ + nn0] = pk;
            } else {
                #pragma unroll
                for (int r = 0; r < 4; ++r) {
                    const int row = row_base + m * 16 + lk * 4 + r;
                    const float v = acc[m][n][r] + bc;
                    if (EPI == 0)
                        ((unsigned short*)outp)[(size_t)row * D_MODEL + col] = f2bf(v);
                    if (EPI == 2)
                        ((unsigned short*)outp)[(size_t)row * D_MODEL + col] = f2bf(fmaxf(v, 0.f));
                    if (EPI == 3)
                        ((float*)outp)[(size_t)row * D_MODEL + col] = v + res[(size_t)row * D_MODEL + col];
                }
            }
        }
    }
}

// ---------------------------------------------------------------------------
// Flash attention, bf16 MFMA. grid: (SEQ/64, NHEADS, BATCH), block 256.
// 4 waves x 16 q-rows; K/V 64-key tiles in padded LDS (72-elem rows).
// q16/k16: [MROWS][1024] bf16 (head h at cols h*64..). vt: [B*1024][SEQ] bf16.
// Output: natural layout omha[b,n][h*64+e] (fp32); LN1 un-permutes.
// ---------------------------------------------------------------------------
__global__ __launch_bounds__(256) void attn_mfma(
    const unsigned short* __restrict__ q16,
    const unsigned short* __restrict__ k16,
    const unsigned short* __restrict__ vt,
    float* __restrict__ omha)
{
    const int qt = blockIdx.x;
    const int h  = blockIdx.y;
    const int b  = blockIdx.z;
    const int tid = threadIdx.x;
    const int l  = tid & 63, w = tid >> 6;
    const int lr = l & 15, lk = l >> 4;

    __shared__ unsigned short Ks[64 * 72];   // Ks[key][e]
    __shared__ unsigned short Vs[64 * 72];   // Vs[e][key]   (V^T rows)
    __shared__ unsigned short Ps[4][16 * 72];

    // Q fragments (A-layout): rows = qt*64 + w*16 + lr
    const size_t qrow = ((size_t)b * SEQ + qt * 64 + w * 16 + lr) * D_MODEL + h * DHEAD;
    const bf16x8 qf0 = *(const bf16x8*)&q16[qrow + lk * 8];
    const bf16x8 qf1 = *(const bf16x8*)&q16[qrow + 32 + lk * 8];

    f32x4 O[4] = {};
    float mrow[4] = {-1e30f, -1e30f, -1e30f, -1e30f};
    float lrow[4] = {0.f, 0.f, 0.f, 0.f};

    // staging: thread covers rows (tid>>3) and (tid>>3)+32, cols (tid&7)*8..+7
    const int str = tid >> 3;            // 0..31
    const int stc = (tid & 7) * 8;       // 0..56
    const size_t kbase = (size_t)b * SEQ * D_MODEL + h * DHEAD;
    const size_t vbase = ((size_t)b * 1024 + h * DHEAD) * SEQ;

    for (int kt = 0; kt < SEQ / 64; ++kt) {
        __syncthreads();
        *(u16x8*)&Ks[str * 72 + stc]        = *(const u16x8*)&k16[kbase + (size_t)(kt * 64 + str) * D_MODEL + stc];
        *(u16x8*)&Ks[(str + 32) * 72 + stc] = *(const u16x8*)&k16[kbase + (size_t)(kt * 64 + str + 32) * D_MODEL + stc];
        *(u16x8*)&Vs[str * 72 + stc]        = *(const u16x8*)&vt [vbase + (size_t)str * SEQ + kt * 64 + stc];
        *(u16x8*)&Vs[(str + 32) * 72 + stc] = *(const u16x8*)&vt [vbase + (size_t)(str + 32) * SEQ + kt * 64 + stc];
        __syncthreads();

        // S = Q.K^T * (1/32)
        f32x4 sf[4];
        #pragma unroll
        for (int f = 0; f < 4; ++f) {
            const bf16x8 kf0 = *(const bf16x8*)&Ks[(f * 16 + lr) * 72 + lk * 8];
            const bf16x8 kf1 = *(const bf16x8*)&Ks[(f * 16 + lr) * 72 + 32 + lk * 8];
            f32x4 s = {};
            s = __builtin_amdgcn_mfma_f32_16x16x32_bf16(qf0, kf0, s, 0, 0, 0);
            s = __builtin_amdgcn_mfma_f32_16x16x32_bf16(qf1, kf1, s, 0, 0, 0);
            s *= 0.03125f;
            sf[f] = s;
        }

        // online softmax (row q = lk*4 + r, replicated across the 16 lr lanes)
        float alpha[4];
        #pragma unroll
        for (int r = 0; r < 4; ++r) {
            float mx = fmaxf(fmaxf(sf[0][r], sf[1][r]), fmaxf(sf[2][r], sf[3][r]));
            mx = fmaxf(mx, __shfl_xor(mx, 1));
            mx = fmaxf(mx, __shfl_xor(mx, 2));
            mx = fmaxf(mx, __shfl_xor(mx, 4));
            mx = fmaxf(mx, __shfl_xor(mx, 8));
            const float mnew = fmaxf(mrow[r], mx);
            alpha[r] = __expf(mrow[r] - mnew);
            mrow[r] = mnew;
        }
        float psum[4] = {0.f, 0.f, 0.f, 0.f};
        #pragma unroll
        for (int f = 0; f < 4; ++f)
            #pragma unroll
            for (int r = 0; r < 4; ++r) {
                const float p = __expf(sf[f][r] - mrow[r]);
                psum[r] += p;
                Ps[w][(lk * 4 + r) * 72 + f * 16 + lr] = f2bf(p);
            }
        #pragma unroll
        for (int r = 0; r < 4; ++r) {
            float ps = psum[r];
            ps += __shfl_xor(ps, 1);
            ps += __shfl_xor(ps, 2);
            ps += __shfl_xor(ps, 4);
            ps += __shfl_xor(ps, 8);
            lrow[r] = lrow[r] * alpha[r] + ps;
        }
        #pragma unroll
        for (int f = 0; f < 4; ++f)
            #pragma unroll
            for (int r = 0; r < 4; ++r)
                O[f][r] *= alpha[r];

        // O += P.V  (P per-wave from LDS in A-layout; V^T rows give B-frags)
        const bf16x8 pa0 = *(const bf16x8*)&Ps[w][lr * 72 + lk * 8];
        const bf16x8 pa1 = *(const bf16x8*)&Ps[w][lr * 72 + 32 + lk * 8];
        #pragma unroll
        for (int f = 0; f < 4; ++f) {
            const bf16x8 vf0 = *(const bf16x8*)&Vs[(f * 16 + lr) * 72 + lk * 8];
            const bf16x8 vf1 = *(const bf16x8*)&Vs[(f * 16 + lr) * 72 + 32 + lk * 8];
            O[f] = __builtin_amdgcn_mfma_f32_16x16x32_bf16(pa0, vf0, O[f], 0, 0, 0);
            O[f] = __builtin_amdgcn_mfma_f32_16x16x32_bf16(pa1, vf1, O[f], 0, 0, 0);
        }
    }

    #pragma unroll
    for (int f = 0; f < 4; ++f)
        #pragma unroll
        for (int r = 0; r < 4; ++r) {
            const float ov = O[f][r] / lrow[r];
            omha[((size_t)b * SEQ + qt * 64 + w * 16 + lk * 4 + r) * D_MODEL + h * DHEAD + f * 16 + lr] = ov;
        }
}

// ---------------------------------------------------------------------------
// LN1: x[c] = mha_natural[(c&15)*64 + (c>>4)] + queries[c] (head un-interleave
// via LDS), then LayerNorm; writes h fp32 and h bf16.  grid (MROWS), 256 thr.
// ---------------------------------------------------------------------------
__global__ __launch_bounds__(256) void ln1_kernel(
    const float* __restrict__ mha, const float* __restrict__ qres,
    const float* __restrict__ g, const float* __restrict__ be,
    float* __restrict__ hf, unsigned short* __restrict__ h16)
{
    const int row = blockIdx.x, tid = threadIdx.x;
    const size_t base = (size_t)row * D_MODEL;
    __shared__ float buf[D_MODEL];

    *(float4*)&buf[tid * 4] = *(const float4*)&mha[base + tid * 4];
    __syncthreads();

    const float4 qv = *(const float4*)&qres[base + tid * 4];
    const float qa[4] = {qv.x, qv.y, qv.z, qv.w};
    float x[4], s = 0.f, sq = 0.f;
    #pragma unroll
    for (int j = 0; j < 4; ++j) {
        const int c = tid * 4 + j;
        x[j] = buf[(c & 15) * 64 + (c >> 4)] + qa[j];
        s += x[j]; sq += x[j] * x[j];
    }
    #pragma unroll
    for (int off = 32; off >= 1; off >>= 1) {
        s  += __shfl_down(s,  off);
        sq += __shfl_down(sq, off);
    }
    __shared__ float sa[4], sb[4];
    if ((tid & 63) == 0) { sa[tid >> 6] = s; sb[tid >> 6] = sq; }
    __syncthreads();
    const float tot = sa[0] + sa[1] + sa[2] + sa[3];
    const float tsq = sb[0] + sb[1] + sb[2] + sb[3];
    const float mean = tot * (1.f / D_MODEL);
    const float var  = tsq * (1.f / D_MODEL) - mean * mean;
    const float rstd = rsqrtf(var + 1e-5f);

    const float4 gv = *(const float4*)&g[tid * 4];
    const float4 bv = *(const float4*)&be[tid * 4];
    const float ga[4] = {gv.x, gv.y, gv.z, gv.w};
    const float ba[4] = {bv.x, bv.y, bv.z, bv.w};
    float y[4];
    #pragma unroll
    for (int j = 0; j < 4; ++j) y[j] = (x[j] - mean) * rstd * ga[j] + ba[j];
    float4 of; of.x = y[0]; of.y = y[1]; of.z = y[2]; of.w = y[3];
    *(float4*)&hf[base + tid * 4] = of;
    unsigned short h4[4];
    #pragma unroll
    for (int j = 0; j < 4; ++j) h4[j] = f2bf(y[j]);
    *(uint2*)&h16[base + tid * 4] = *(uint2*)h4;
}

// ---------------------------------------------------------------------------
// LN2: plain LayerNorm fp32 -> d_out. grid (MROWS), 256 thr.
// ---------------------------------------------------------------------------
__global__ __launch_bounds__(256) void ln2_kernel(
    const float* __restrict__ xin,
    const float* __restrict__ g, const float* __restrict__ be,
    float* __restrict__ out)
{
    const int row = blockIdx.x, tid = threadIdx.x;
    const size_t base = (size_t)row * D_MODEL;
    float4 xv = *(const float4*)&xin[base + tid * 4];
    float s  = xv.x + xv.y + xv.z + xv.w;
    float sq = xv.x*xv.x + xv.y*xv.y + xv.z*xv.z + xv.w*xv.w;
    #pragma unroll
    for (int off = 32; off >= 1; off >>= 1) {
        s  += __shfl_down(s,  off);
        sq += __shfl_down(sq, off);
    }
    __shared__ float sa[4], sb[4];
    if ((tid & 63) == 0) { sa[tid >> 6] = s; sb[tid >> 6] = sq; }
    __syncthreads();
    const float tot = sa[0] + sa[1] + sa[2] + sa[3];
    const float tsq = sb[0] + sb[1] + sb[2] + sb[3];
    const float mean = tot * (1.f / D_MODEL);
    const float var  = tsq * (1.f / D_MODEL) - mean * mean;
    const float rstd = rsqrtf(var + 1e-5f);
    const float4 gv = *(const float4*)&g[tid * 4];
    const float4 bv = *(const float4*)&be[tid * 4];
    float4 ov;
    ov.x = (xv.x - mean) * rstd * gv.x + bv.x;
    ov.y = (xv.y - mean) * rstd * gv.y + bv.y;
    ov.z = (xv.z - mean) * rstd * gv.z + bv.z;
    ov.w = (xv.w - mean) * rstd * gv.w + bv.w;
    *(float4*)&out[base + tid * 4] = ov;
}

// ---------------------------------------------------------------------------
extern "C" void kernel_launch(void* const* d_in, const int* in_sizes, int n_in,
                              void* d_out, int out_size, void* d_ws, size_t ws_size,
                              hipStream_t stream)
{
    (void)in_sizes; (void)n_in; (void)out_size; (void)ws_size;
    const float* queries = (const float*)d_in[0];
    const float* keys    = (const float*)d_in[1];
    const float* values  = (const float*)d_in[2];
    const float* Wq = (const float*)d_in[3];
    const float* bq = (const float*)d_in[4];
    const float* Wk = (const float*)d_in[5];
    const float* bk = (const float*)d_in[6];
    const float* Wv = (const float*)d_in[7];
    const float* bv = (const float*)d_in[8];
    const float* W1 = (const float*)d_in[9];
    const float* b1 = (const float*)d_in[10];
    const float* W2 = (const float*)d_in[11];
    const float* b2 = (const float*)d_in[12];
    const float* g1 = (const float*)d_in[13];
    const float* be1= (const float*)d_in[14];
    const float* g2 = (const float*)d_in[15];
    const float* be2= (const float*)d_in[16];
    float* out = (float*)d_out;

    // ---- workspace layout (111 MB total, with hazard-checked overlaps) ----
    const size_t SZ16 = (size_t)MROWS * D_MODEL * 2;   // 16.78 MB bf16 act
    const size_t SZW  = (size_t)D_MODEL * D_MODEL * 2; // 2.10 MB bf16 weight
    char* p = (char*)d_ws;
    unsigned short* XQ  = (unsigned short*)(p);
    unsigned short* XK  = (unsigned short*)(p + SZ16);
    unsigned short* XV  = (unsigned short*)(p + 2 * SZ16);
    unsigned short* TWq = (unsigned short*)(p + 3 * SZ16);
    unsigned short* TWk = (unsigned short*)(p + 3 * SZ16 + SZW);
    unsigned short* TWv = (unsigned short*)(p + 3 * SZ16 + 2 * SZW);
    unsigned short* TW1 = (unsigned short*)(p + 3 * SZ16 + 3 * SZW);
    unsigned short* TW2 = (unsigned short*)(p + 3 * SZ16 + 4 * SZW);
    char* p2 = p + 3 * SZ16 + 5 * SZW;
    unsigned short* Q16 = (unsigned short*)(p2);
    unsigned short* K16 = (unsigned short*)(p2 + SZ16);
    unsigned short* VT  = (unsigned short*)(p2 + 2 * SZ16);
    // overlapped reuse (producer dead before reuse):
    float*          MHA = (float*)XQ;    // attn out: XQ/XK dead after Q16/K16
    float*          HF  = (float*)Q16;   // LN1 fp32: Q16/K16 dead after attn
    unsigned short* H16 = VT;            // LN1 bf16: VT dead after attn
    unsigned short* F1  = XV;            // ffn1 out: XV dead after VT
    float*          Y   = MHA;           // ffn2 out: MHA dead after LN1

    const dim3 blk(256);

    convert3<<<dim3(MROWS * D_MODEL / (256 * 8), 1, 3), blk, 0, stream>>>(
        queries, keys, values, XQ, XK, XV);
    tconvW<<<dim3(32, 32, 5), blk, 0, stream>>>(
        Wq, Wk, Wv, W1, W2, TWq, TWk, TWv, TW1, TW2);

    const dim3 gg(MROWS / 128, D_MODEL / 128);
    gemm128<0><<<gg, blk, 0, stream>>>(XQ, TWq, bq, nullptr, Q16);
    gemm128<0><<<gg, blk, 0, stream>>>(XK, TWk, bk, nullptr, K16);
    gemm128<1><<<gg, blk, 0, stream>>>(XV, TWv, bv, nullptr, VT);

    attn_mfma<<<dim3(SEQ / 64, NHEADS, BATCH), blk, 0, stream>>>(Q16, K16, VT, MHA);

    ln1_kernel<<<dim3(MROWS), blk, 0, stream>>>(MHA, queries, g1, be1, HF, H16);

    gemm128<2><<<gg, blk, 0, stream>>>(H16, TW1, b1, nullptr, F1);
    gemm128<3><<<gg, blk, 0, stream>>>(F1,  TW2, b2, HF, Y);

    ln2_kernel<<<dim3(MROWS), blk, 0, stream>>>(Y, g2, be2, out);
}

// Round 8
// 409.590 us; speedup vs baseline: 1.1275x; 1.1275x over previous
//
#include <hip/hip_runtime.h>
#include <math.h>

#define D_MODEL 1024
#define NHEADS  16
#define DHEAD   64
#define BATCH   8
#define SEQ     1024
#define MROWS   (BATCH*SEQ)   // 8192

typedef short          bf16x8 __attribute__((ext_vector_type(8)));
typedef unsigned short u16x8  __attribute__((ext_vector_type(8)));
typedef float          f32x4  __attribute__((ext_vector_type(4)));

typedef __attribute__((address_space(1))) void* gvp;   // global
typedef __attribute__((address_space(3))) void* svp;   // LDS

__device__ __forceinline__ unsigned short f2bf(float f) {
    unsigned int u = __float_as_uint(f);
    u = u + 0x7fffu + ((u >> 16) & 1u);      // round-to-nearest-even
    return (unsigned short)(u >> 16);
}

// ---------------------------------------------------------------------------
// fp32 -> bf16 elementwise convert for queries/keys/values. 8 elems/thread.
// ---------------------------------------------------------------------------
__global__ __launch_bounds__(256) void convert3(
    const float* __restrict__ q, const float* __restrict__ k, const float* __restrict__ v,
    unsigned short* __restrict__ oq, unsigned short* __restrict__ ok, unsigned short* __restrict__ ov)
{
    const float* in; unsigned short* out;
    if (blockIdx.z == 0)      { in = q; out = oq; }
    else if (blockIdx.z == 1) { in = k; out = ok; }
    else                      { in = v; out = ov; }
    const size_t i = ((size_t)blockIdx.x * 256 + threadIdx.x) * 8;
    const float4 a = *(const float4*)(in + i);
    const float4 b = *(const float4*)(in + i + 4);
    u16x8 o;
    o[0] = f2bf(a.x); o[1] = f2bf(a.y); o[2] = f2bf(a.z); o[3] = f2bf(a.w);
    o[4] = f2bf(b.x); o[5] = f2bf(b.y); o[6] = f2bf(b.z); o[7] = f2bf(b.w);
    *(u16x8*)(out + i) = o;
}

// ---------------------------------------------------------------------------
// Transpose-convert weights to bf16 Bt[n][k] layout.
// z = 0..2: Wq/Wk/Wv ([H][1024][64], virtual col n = h*64+e); z = 3..4: W1/W2.
// grid: (32, 32, 5), block 256 (32x8).
// ---------------------------------------------------------------------------
__global__ __launch_bounds__(256) void tconvW(
    const float* __restrict__ Wq, const float* __restrict__ Wk, const float* __restrict__ Wv,
    const float* __restrict__ W1, const float* __restrict__ W2,
    unsigned short* __restrict__ Tq, unsigned short* __restrict__ Tk, unsigned short* __restrict__ Tv,
    unsigned short* __restrict__ T1, unsigned short* __restrict__ T2)
{
    const int z = blockIdx.z;
    const float* in; unsigned short* out;
    if (z == 0)      { in = Wq; out = Tq; }
    else if (z == 1) { in = Wk; out = Tk; }
    else if (z == 2) { in = Wv; out = Tv; }
    else if (z == 3) { in = W1; out = T1; }
    else             { in = W2; out = T2; }
    const int proj = (z < 3);

    __shared__ float t[32][33];
    const int c0 = blockIdx.x * 32, r0 = blockIdx.y * 32;
    const int tx = threadIdx.x & 31, ty = threadIdx.x >> 5;

    #pragma unroll
    for (int i = 0; i < 4; ++i) {
        const int r = r0 + ty + i * 8;
        const size_t addr = proj
            ? ((size_t)(c0 >> 6) * (D_MODEL * DHEAD) + (size_t)r * DHEAD + (c0 & 63) + tx)
            : ((size_t)r * D_MODEL + c0 + tx);
        t[ty + i * 8][tx] = in[addr];
    }
    __syncthreads();
    #pragma unroll
    for (int i = 0; i < 4; ++i) {
        const int n = c0 + ty + i * 8;                 // output row (col of W)
        out[(size_t)n * D_MODEL + r0 + tx] = f2bf(t[tx][ty + i * 8]);
    }
}

// ---------------------------------------------------------------------------
// Fused Q/K/V projection GEMM, one dispatch. grid: (M/128, N/128, 3).
// z selects (A, Bt, bias, out, epilogue). m97 structure: tile 128x128, BK=32,
// 4 waves, linear LDS [128][32] via global_load_lds width=16.
// z=0: Q -> bf16 * (1/32) (folds attention scale); z=1: K -> bf16;
// z=2: V -> bf16 transposed per-head Vt[b*1024+col][n] (ushort4-packed).
// ---------------------------------------------------------------------------
__global__ __launch_bounds__(256) void proj3_gemm(
    const unsigned short* __restrict__ XQ, const unsigned short* __restrict__ XK,
    const unsigned short* __restrict__ XV,
    const unsigned short* __restrict__ TWq, const unsigned short* __restrict__ TWk,
    const unsigned short* __restrict__ TWv,
    const float* __restrict__ bq, const float* __restrict__ bk, const float* __restrict__ bv,
    unsigned short* __restrict__ Q16, unsigned short* __restrict__ K16,
    unsigned short* __restrict__ VT)
{
    const int z = blockIdx.z;
    const unsigned short* A  = (z == 0) ? XQ  : (z == 1) ? XK  : XV;
    const unsigned short* Bt = (z == 0) ? TWq : (z == 1) ? TWk : TWv;
    const float* bias        = (z == 0) ? bq  : (z == 1) ? bk  : bv;
    const float oscale       = (z == 0) ? 0.03125f : 1.0f;

    const int m0 = blockIdx.x * 128;
    const int n0 = blockIdx.y * 128;
    const int tid = threadIdx.x;
    const int l  = tid & 63;
    const int w  = tid >> 6;
    const int wr = w >> 1, wc = w & 1;
    const int lr = l & 15, lk = l >> 4;

    __shared__ unsigned short As[128 * 32];
    __shared__ unsigned short Bs[128 * 32];

    f32x4 acc[4][4] = {};

    const int r_a = (l >> 2);
    const int c_a = (l & 3) * 8;

    for (int k0 = 0; k0 < D_MODEL; k0 += 32) {
        #pragma unroll
        for (int i = 0; i < 2; ++i) {
            const int c   = w * 2 + i;
            const int row = c * 16 + r_a;
            __builtin_amdgcn_global_load_lds(
                (gvp)(void*)&A [(size_t)(m0 + row) * D_MODEL + k0 + c_a],
                (svp)(void*)&As[c * 512], 16, 0, 0);
            __builtin_amdgcn_global_load_lds(
                (gvp)(void*)&Bt[(size_t)(n0 + row) * D_MODEL + k0 + c_a],
                (svp)(void*)&Bs[c * 512], 16, 0, 0);
        }
        __syncthreads();

        bf16x8 af[4], bf[4];
        #pragma unroll
        for (int m = 0; m < 4; ++m)
            af[m] = *(const bf16x8*)&As[(wr * 64 + m * 16 + lr) * 32 + lk * 8];
        #pragma unroll
        for (int n = 0; n < 4; ++n)
            bf[n] = *(const bf16x8*)&Bs[(wc * 64 + n * 16 + lr) * 32 + lk * 8];
        #pragma unroll
        for (int m = 0; m < 4; ++m)
            #pragma unroll
            for (int n = 0; n < 4; ++n)
                acc[m][n] = __builtin_amdgcn_mfma_f32_16x16x32_bf16(af[m], bf[n], acc[m][n], 0, 0, 0);
        __syncthreads();
    }

    const int col_base = n0 + wc * 64;
    const int row_base = m0 + wr * 64;
    #pragma unroll
    for (int n = 0; n < 4; ++n) {
        const int col  = col_base + n * 16 + lr;
        const float bc = bias[col];
        #pragma unroll
        for (int m = 0; m < 4; ++m) {
            if (z == 2) {
                // rows lk*4..+3 = 4 consecutive seq positions -> packed 8B store
                const int row0 = row_base + m * 16 + lk * 4;
                const int b = row0 >> 10, nn0 = row0 & 1023;
                ushort4 pk;
                pk.x = f2bf(acc[m][n][0] + bc);
                pk.y = f2bf(acc[m][n][1] + bc);
                pk.z = f2bf(acc[m][n][2] + bc);
                pk.w = f2bf(acc[m][n][3] + bc);
                *(ushort4*)&VT[((size_t)b * 1024 + col) * SEQ + nn0] = pk;
            } else {
                unsigned short* outp = (z == 0) ? Q16 : K16;
                #pragma unroll
                for (int r = 0; r < 4; ++r) {
                    const int row = row_base + m * 16 + lk * 4 + r;
                    outp[(size_t)row * D_MODEL + col] = f2bf((acc[m][n][r] + bc) * oscale);
                }
            }
        }
    }
}

// ---------------------------------------------------------------------------
// FFN GEMM (m97 structure), tile 128x128, BK=32, 4 waves.
// EPI: 2 = bias+relu->bf16, 3 = bias+res(f32)->f32.  grid: (64, 8)
// ---------------------------------------------------------------------------
template<int EPI>
__global__ __launch_bounds__(256) void gemm128(
    const unsigned short* __restrict__ A,
    const unsigned short* __restrict__ Bt,
    const float* __restrict__ bias,
    const float* __restrict__ res,
    void* __restrict__ outp)
{
    const int m0 = blockIdx.x * 128;
    const int n0 = blockIdx.y * 128;
    const int tid = threadIdx.x;
    const int l  = tid & 63;
    const int w  = tid >> 6;
    const int wr = w >> 1, wc = w & 1;
    const int lr = l & 15, lk = l >> 4;

    __shared__ unsigned short As[128 * 32];
    __shared__ unsigned short Bs[128 * 32];

    f32x4 acc[4][4] = {};

    const int r_a = (l >> 2);
    const int c_a = (l & 3) * 8;

    for (int k0 = 0; k0 < D_MODEL; k0 += 32) {
        #pragma unroll
        for (int i = 0; i < 2; ++i) {
            const int c   = w * 2 + i;
            const int row = c * 16 + r_a;
            __builtin_amdgcn_global_load_lds(
                (gvp)(void*)&A [(size_t)(m0 + row) * D_MODEL + k0 + c_a],
                (svp)(void*)&As[c * 512], 16, 0, 0);
            __builtin_amdgcn_global_load_lds(
                (gvp)(void*)&Bt[(size_t)(n0 + row) * D_MODEL + k0 + c_a],
                (svp)(void*)&Bs[c * 512], 16, 0, 0);
        }
        __syncthreads();

        bf16x8 af[4], bf[4];
        #pragma unroll
        for (int m = 0; m < 4; ++m)
            af[m] = *(const bf16x8*)&As[(wr * 64 + m * 16 + lr) * 32 + lk * 8];
        #pragma unroll
        for (int n = 0; n < 4; ++n)
            bf[n] = *(const bf16x8*)&Bs[(wc * 64 + n * 16 + lr) * 32 + lk * 8];
        #pragma unroll
        for (int m = 0; m < 4; ++m)
            #pragma unroll
            for (int n = 0; n < 4; ++n)
                acc[m][n] = __builtin_amdgcn_mfma_f32_16x16x32_bf16(af[m], bf[n], acc[m][n], 0, 0, 0);
        __syncthreads();
    }

    const int col_base = n0 + wc * 64;
    const int row_base = m0 + wr * 64;
    #pragma unroll
    for (int n = 0; n < 4; ++n) {
        const int col  = col_base + n * 16 + lr;
        const float bc = bias[col];
        #pragma unroll
        for (int m = 0; m < 4; ++m) {
            #pragma unroll
            for (int r = 0; r < 4; ++r) {
                const int row = row_base + m * 16 + lk * 4 + r;
                float v = acc[m][n][r] + bc;
                if (EPI == 2)
                    ((unsigned short*)outp)[(size_t)row * D_MODEL + col] = f2bf(fmaxf(v, 0.f));
                if (EPI == 3)
                    ((float*)outp)[(size_t)row * D_MODEL + col] = v + res[(size_t)row * D_MODEL + col];
            }
        }
    }
}

// ---------------------------------------------------------------------------
// Flash attention, bf16 MFMA, swapped-QK^T per-lane softmax.
// grid: (SEQ/64, NHEADS, BATCH), block 256 = 4 waves x 16 q-rows.
// S^T = mfma(K_frag, Q_frag): lane holds 16 scores all for q-row (lane&15),
// keys f*16 + (lane>>4)*4 + r.  Softmax = in-lane reduce + shfl_xor(16,32).
// P packed via v_cvt_pk_bf16_f32, stored b64 to Ps[q][key]; PV reads Ps rows
// as A-fragments.  Q is pre-scaled by 1/32 in its projection epilogue.
// T5: s_setprio(1) around MFMA clusters (multi-block/CU wave diversity here).
// ---------------------------------------------------------------------------
__global__ __launch_bounds__(256) void attn_mfma(
    const unsigned short* __restrict__ q16,
    const unsigned short* __restrict__ k16,
    const unsigned short* __restrict__ vt,
    float* __restrict__ omha)
{
    const int qt = blockIdx.x;
    const int h  = blockIdx.y;
    const int b  = blockIdx.z;
    const int tid = threadIdx.x;
    const int l  = tid & 63, w = tid >> 6;
    const int lr = l & 15, lk = l >> 4;

    __shared__ unsigned short Ks[64 * 72];   // Ks[key][e]
    __shared__ unsigned short Vs[64 * 72];   // Vs[e][key]   (V^T rows)
    __shared__ unsigned short Ps[4][16 * 72];// per-wave P[q][key]

    const size_t qrow = ((size_t)b * SEQ + qt * 64 + w * 16 + lr) * D_MODEL + h * DHEAD;
    const bf16x8 qf0 = *(const bf16x8*)&q16[qrow + lk * 8];
    const bf16x8 qf1 = *(const bf16x8*)&q16[qrow + 32 + lk * 8];

    f32x4 O[4] = {};
    float m_l = -1e30f;   // running max for q = lr
    float l_l = 0.f;      // running denom for q = lr

    const int str = tid >> 3;            // 0..31
    const int stc = (tid & 7) * 8;       // 0..56
    const size_t kbase = (size_t)b * SEQ * D_MODEL + h * DHEAD;
    const size_t vbase = ((size_t)b * 1024 + h * DHEAD) * SEQ;

    for (int kt = 0; kt < SEQ / 64; ++kt) {
        __syncthreads();
        *(u16x8*)&Ks[str * 72 + stc]        = *(const u16x8*)&k16[kbase + (size_t)(kt * 64 + str) * D_MODEL + stc];
        *(u16x8*)&Ks[(str + 32) * 72 + stc] = *(const u16x8*)&k16[kbase + (size_t)(kt * 64 + str + 32) * D_MODEL + stc];
        *(u16x8*)&Vs[str * 72 + stc]        = *(const u16x8*)&vt [vbase + (size_t)str * SEQ + kt * 64 + stc];
        *(u16x8*)&Vs[(str + 32) * 72 + stc] = *(const u16x8*)&vt [vbase + (size_t)(str + 32) * SEQ + kt * 64 + stc];
        __syncthreads();

        // S^T = K.Q^T -> st[f][r] = S[q=lr][key = f*16 + lk*4 + r]
        f32x4 st[4];
        __builtin_amdgcn_s_setprio(1);
        #pragma unroll
        for (int f = 0; f < 4; ++f) {
            const bf16x8 kf0 = *(const bf16x8*)&Ks[(f * 16 + lr) * 72 + lk * 8];
            const bf16x8 kf1 = *(const bf16x8*)&Ks[(f * 16 + lr) * 72 + 32 + lk * 8];
            f32x4 s = {};
            s = __builtin_amdgcn_mfma_f32_16x16x32_bf16(kf0, qf0, s, 0, 0, 0);
            s = __builtin_amdgcn_mfma_f32_16x16x32_bf16(kf1, qf1, s, 0, 0, 0);
            st[f] = s;
        }
        __builtin_amdgcn_s_setprio(0);

        // per-lane row max, then across the lk groups
        float mx = st[0][0];
        #pragma unroll
        for (int f = 0; f < 4; ++f)
            #pragma unroll
            for (int r = 0; r < 4; ++r) mx = fmaxf(mx, st[f][r]);
        mx = fmaxf(mx, __shfl_xor(mx, 16));
        mx = fmaxf(mx, __shfl_xor(mx, 32));
        const float mnew = fmaxf(m_l, mx);
        const float alpha = __expf(m_l - mnew);
        m_l = mnew;

        float psum = 0.f;
        #pragma unroll
        for (int f = 0; f < 4; ++f)
            #pragma unroll
            for (int r = 0; r < 4; ++r) {
                const float pv = __expf(st[f][r] - mnew);
                st[f][r] = pv;
                psum += pv;
            }
        psum += __shfl_xor(psum, 16);
        psum += __shfl_xor(psum, 32);
        l_l = l_l * alpha + psum;

        // pack P -> bf16 pairs, one b64 store per f
        #pragma unroll
        for (int f = 0; f < 4; ++f) {
            unsigned int plo, phi;
            asm("v_cvt_pk_bf16_f32 %0, %1, %2" : "=v"(plo) : "v"(st[f][0]), "v"(st[f][1]));
            asm("v_cvt_pk_bf16_f32 %0, %1, %2" : "=v"(phi) : "v"(st[f][2]), "v"(st[f][3]));
            uint2 pk; pk.x = plo; pk.y = phi;
            *(uint2*)&Ps[w][lr * 72 + f * 16 + lk * 4] = pk;
        }

        // rescale O rows unless no row max grew
        if (!__all(alpha == 1.0f)) {
            const float a0 = __shfl(alpha, lk * 4 + 0);
            const float a1 = __shfl(alpha, lk * 4 + 1);
            const float a2 = __shfl(alpha, lk * 4 + 2);
            const float a3 = __shfl(alpha, lk * 4 + 3);
            #pragma unroll
            for (int f = 0; f < 4; ++f) {
                O[f][0] *= a0; O[f][1] *= a1; O[f][2] *= a2; O[f][3] *= a3;
            }
        }

        // O += P.V
        const bf16x8 pa0 = *(const bf16x8*)&Ps[w][lr * 72 + lk * 8];
        const bf16x8 pa1 = *(const bf16x8*)&Ps[w][lr * 72 + 32 + lk * 8];
        __builtin_amdgcn_s_setprio(1);
        #pragma unroll
        for (int f = 0; f < 4; ++f) {
            const bf16x8 vf0 = *(const bf16x8*)&Vs[(f * 16 + lr) * 72 + lk * 8];
            const bf16x8 vf1 = *(const bf16x8*)&Vs[(f * 16 + lr) * 72 + 32 + lk * 8];
            O[f] = __builtin_amdgcn_mfma_f32_16x16x32_bf16(pa0, vf0, O[f], 0, 0, 0);
            O[f] = __builtin_amdgcn_mfma_f32_16x16x32_bf16(pa1, vf1, O[f], 0, 0, 0);
        }
        __builtin_amdgcn_s_setprio(0);
    }

    const float il0 = 1.f / __shfl(l_l, lk * 4 + 0);
    const float il1 = 1.f / __shfl(l_l, lk * 4 + 1);
    const float il2 = 1.f / __shfl(l_l, lk * 4 + 2);
    const float il3 = 1.f / __shfl(l_l, lk * 4 + 3);
    #pragma unroll
    for (int f = 0; f < 4; ++f) {
        const size_t obase = ((size_t)b * SEQ + qt * 64 + w * 16 + lk * 4) * D_MODEL + h * DHEAD + f * 16 + lr;
        omha[obase]               = O[f][0] * il0;
        omha[obase + D_MODEL]     = O[f][1] * il1;
        omha[obase + 2 * D_MODEL] = O[f][2] * il2;
        omha[obase + 3 * D_MODEL] = O[f][3] * il3;
    }
}

// ---------------------------------------------------------------------------
// LN1: x[c] = mha_natural[(c&15)*64 + (c>>4)] + queries[c] (head un-interleave
// via LDS), then LayerNorm; writes h fp32 and h bf16.  grid (MROWS), 256 thr.
// ---------------------------------------------------------------------------
__global__ __launch_bounds__(256) void ln1_kernel(
    const float* __restrict__ mha, const float* __restrict__ qres,
    const float* __restrict__ g, const float* __restrict__ be,
    float* __restrict__ hf, unsigned short* __restrict__ h16)
{
    const int row = blockIdx.x, tid = threadIdx.x;
    const size_t base = (size_t)row * D_MODEL;
    __shared__ float buf[D_MODEL];

    *(float4*)&buf[tid * 4] = *(const float4*)&mha[base + tid * 4];
    __syncthreads();

    const float4 qv = *(const float4*)&qres[base + tid * 4];
    const float qa[4] = {qv.x, qv.y, qv.z, qv.w};
    float x[4], s = 0.f, sq = 0.f;
    #pragma unroll
    for (int j = 0; j < 4; ++j) {
        const int c = tid * 4 + j;
        x[j] = buf[(c & 15) * 64 + (c >> 4)] + qa[j];
        s += x[j]; sq += x[j] * x[j];
    }
    #pragma unroll
    for (int off = 32; off >= 1; off >>= 1) {
        s  += __shfl_down(s,  off);
        sq += __shfl_down(sq, off);
    }
    __shared__ float sa[4], sb[4];
    if ((tid & 63) == 0) { sa[tid >> 6] = s; sb[tid >> 6] = sq; }
    __syncthreads();
    const float tot = sa[0] + sa[1] + sa[2] + sa[3];
    const float tsq = sb[0] + sb[1] + sb[2] + sb[3];
    const float mean = tot * (1.f / D_MODEL);
    const float var  = tsq * (1.f / D_MODEL) - mean * mean;
    const float rstd = rsqrtf(var + 1e-5f);

    const float4 gv = *(const float4*)&g[tid * 4];
    const float4 bv = *(const float4*)&be[tid * 4];
    const float ga[4] = {gv.x, gv.y, gv.z, gv.w};
    const float ba[4] = {bv.x, bv.y, bv.z, bv.w};
    float y[4];
    #pragma unroll
    for (int j = 0; j < 4; ++j) y[j] = (x[j] - mean) * rstd * ga[j] + ba[j];
    float4 of; of.x = y[0]; of.y = y[1]; of.z = y[2]; of.w = y[3];
    *(float4*)&hf[base + tid * 4] = of;
    unsigned short h4[4];
    #pragma unroll
    for (int j = 0; j < 4; ++j) h4[j] = f2bf(y[j]);
    *(uint2*)&h16[base + tid * 4] = *(uint2*)h4;
}

// ---------------------------------------------------------------------------
// LN2: plain LayerNorm fp32 -> d_out. grid (MROWS), 256 thr.
// ---------------------------------------------------------------------------
__global__ __launch_bounds__(256) void ln2_kernel(
    const float* __restrict__ xin,
    const float* __restrict__ g, const float* __restrict__ be,
    float* __restrict__ out)
{
    const int row = blockIdx.x, tid = threadIdx.x;
    const size_t base = (size_t)row * D_MODEL;
    float4 xv = *(const float4*)&xin[base + tid * 4];
    float s  = xv.x + xv.y + xv.z + xv.w;
    float sq = xv.x*xv.x + xv.y*xv.y + xv.z*xv.z + xv.w*xv.w;
    #pragma unroll
    for (int off = 32; off >= 1; off >>= 1) {
        s  += __shfl_down(s,  off);
        sq += __shfl_down(sq, off);
    }
    __shared__ float sa[4], sb[4];
    if ((tid & 63) == 0) { sa[tid >> 6] = s; sb[tid >> 6] = sq; }
    __syncthreads();
    const float tot = sa[0] + sa[1] + sa[2] + sa[3];
    const float tsq = sb[0] + sb[1] + sb[2] + sb[3];
    const float mean = tot * (1.f / D_MODEL);
    const float var  = tsq * (1.f / D_MODEL) - mean * mean;
    const float rstd = rsqrtf(var + 1e-5f);
    const float4 gv = *(const float4*)&g[tid * 4];
    const float4 bv = *(const float4*)&be[tid * 4];
    float4 ov;
    ov.x = (xv.x - mean) * rstd * gv.x + bv.x;
    ov.y = (xv.y - mean) * rstd * gv.y + bv.y;
    ov.z = (xv.z - mean) * rstd * gv.z + bv.z;
    ov.w = (xv.w - mean) * rstd * gv.w + bv.w;
    *(float4*)&out[base + tid * 4] = ov;
}

// ---------------------------------------------------------------------------
extern "C" void kernel_launch(void* const* d_in, const int* in_sizes, int n_in,
                              void* d_out, int out_size, void* d_ws, size_t ws_size,
                              hipStream_t stream)
{
    (void)in_sizes; (void)n_in; (void)out_size; (void)ws_size;
    const float* queries = (const float*)d_in[0];
    const float* keys    = (const float*)d_in[1];
    const float* values  = (const float*)d_in[2];
    const float* Wq = (const float*)d_in[3];
    const float* bq = (const float*)d_in[4];
    const float* Wk = (const float*)d_in[5];
    const float* bk = (const float*)d_in[6];
    const float* Wv = (const float*)d_in[7];
    const float* bv = (const float*)d_in[8];
    const float* W1 = (const float*)d_in[9];
    const float* b1 = (const float*)d_in[10];
    const float* W2 = (const float*)d_in[11];
    const float* b2 = (const float*)d_in[12];
    const float* g1 = (const float*)d_in[13];
    const float* be1= (const float*)d_in[14];
    const float* g2 = (const float*)d_in[15];
    const float* be2= (const float*)d_in[16];
    float* out = (float*)d_out;

    // ---- workspace layout (111 MB total, hazard-checked overlaps) ----
    const size_t SZ16 = (size_t)MROWS * D_MODEL * 2;   // 16.78 MB bf16 act
    const size_t SZW  = (size_t)D_MODEL * D_MODEL * 2; // 2.10 MB bf16 weight
    char* p = (char*)d_ws;
    unsigned short* XQ  = (unsigned short*)(p);
    unsigned short* XK  = (unsigned short*)(p + SZ16);
    unsigned short* XV  = (unsigned short*)(p + 2 * SZ16);
    unsigned short* TWq = (unsigned short*)(p + 3 * SZ16);
    unsigned short* TWk = (unsigned short*)(p + 3 * SZ16 + SZW);
    unsigned short* TWv = (unsigned short*)(p + 3 * SZ16 + 2 * SZW);
    unsigned short* TW1 = (unsigned short*)(p + 3 * SZ16 + 3 * SZW);
    unsigned short* TW2 = (unsigned short*)(p + 3 * SZ16 + 4 * SZW);
    char* p2 = p + 3 * SZ16 + 5 * SZW;
    unsigned short* Q16 = (unsigned short*)(p2);
    unsigned short* K16 = (unsigned short*)(p2 + SZ16);
    unsigned short* VT  = (unsigned short*)(p2 + 2 * SZ16);
    // overlapped reuse (producer dead before reuse):
    float*          MHA = (float*)XQ;    // attn out: XQ/XK dead after proj
    float*          HF  = (float*)Q16;   // LN1 fp32: Q16/K16 dead after attn
    unsigned short* H16 = VT;            // LN1 bf16: VT dead after attn
    unsigned short* F1  = XV;            // ffn1 out: XV dead after proj
    float*          Y   = MHA;           // ffn2 out: MHA dead after LN1

    const dim3 blk(256);

    convert3<<<dim3(MROWS * D_MODEL / (256 * 8), 1, 3), blk, 0, stream>>>(
        queries, keys, values, XQ, XK, XV);
    tconvW<<<dim3(32, 32, 5), blk, 0, stream>>>(
        Wq, Wk, Wv, W1, W2, TWq, TWk, TWv, TW1, TW2);

    // fused Q/K/V projections (Q carries the 1/32 attention scale)
    proj3_gemm<<<dim3(MROWS / 128, D_MODEL / 128, 3), blk, 0, stream>>>(
        XQ, XK, XV, TWq, TWk, TWv, bq, bk, bv, Q16, K16, VT);

    attn_mfma<<<dim3(SEQ / 64, NHEADS, BATCH), blk, 0, stream>>>(Q16, K16, VT, MHA);

    ln1_kernel<<<dim3(MROWS), blk, 0, stream>>>(MHA, queries, g1, be1, HF, H16);

    const dim3 gg(MROWS / 128, D_MODEL / 128);
    gemm128<2><<<gg, blk, 0, stream>>>(H16, TW1, b1, nullptr, F1);
    gemm128<3><<<gg, blk, 0, stream>>>(F1,  TW2, b2, HF, Y);

    ln2_kernel<<<dim3(MROWS), blk, 0, stream>>>(Y, g2, be2, out);
}